// Round 14
// baseline (325.154 us; speedup 1.0000x reference)
//
#include <hip/hip_runtime.h>
#include <hip/hip_bf16.h>
#include <hip/hip_fp16.h>

// Bahdanau location-sensitive attention, fused f16-MFMA implementation.
// R14: R12's winning k_main geometry (128x128, 256 thr, 4 blocks/CU, BK=64,
//      single-buffered) with the f32->f16 A-conversion fused into k_main's
//      write-side staging (R9-proven pattern) -> k_cvt (47 us) eliminated;
//      ctx_part reads enc f32 (L3-hot after k_main, R9-proven ~7 us support).
//      B via gload_lds from Bf[kC][1088]; tail A via gload_lds from locPad
//      (cols 32..63 zeroed -> uniform 2-kk compute, NaN-safe).
// B=32 T=1536 H=1024 CTX=1024 CONV_OUT=32

constexpr int kB = 32, kT = 1536, kH = 1024, kC = 1024, kCO = 32;
constexpr int kM = kB * kT;      // 49152
constexpr int kKp = 1088;        // padded B K: 1024 V | 32 U | 32 zero

typedef _Float16 f16;
typedef _Float16 f16x8 __attribute__((ext_vector_type(8)));
typedef float f32x4 __attribute__((ext_vector_type(4)));

// ---- ws layout (bytes) ----
constexpr size_t WS_B    = 0;                                    // kC*kKp f16  (2.23 MB)
constexpr size_t WS_LOC  = WS_B + (size_t)kC * kKp * 2;          // kM*64 f16   (6.3 MB)
constexpr size_t WS_ADD  = WS_LOC + (size_t)kM * 64 * 2;         // kB*kC f32
constexpr size_t WS_SCR  = WS_ADD + (size_t)kB * kC * 4;         // spart 8*kM f32 / cpart aliased

__device__ __forceinline__ void gload16(const void* g, void* l) {
    __builtin_amdgcn_global_load_lds(
        (const __attribute__((address_space(1))) void*)g,
        (__attribute__((address_space(3))) void*)l, 16, 0, 0);
}

// ---------------------------------------------------------------- B pack [kC][1088] f16 (vectorized)
__global__ void k_prep_b2(const float* __restrict__ V, const float* __restrict__ U,
                          f16* __restrict__ Bf) {
    int c = blockIdx.x, k8 = threadIdx.x;            // active k8 < 136
    if (k8 >= 136) return;
    union { f16 h[8]; int4 q; } u;
    if (k8 < 128) {
        const float* src = V + (size_t)c * kH + k8 * 8;
        float4 a = *(const float4*)src, b = *(const float4*)(src + 4);
        u.h[0] = (f16)a.x; u.h[1] = (f16)a.y; u.h[2] = (f16)a.z; u.h[3] = (f16)a.w;
        u.h[4] = (f16)b.x; u.h[5] = (f16)b.y; u.h[6] = (f16)b.z; u.h[7] = (f16)b.w;
    } else if (k8 < 132) {
        const float* src = U + (size_t)c * kCO + (k8 - 128) * 8;
        float4 a = *(const float4*)src, b = *(const float4*)(src + 4);
        u.h[0] = (f16)a.x; u.h[1] = (f16)a.y; u.h[2] = (f16)a.z; u.h[3] = (f16)a.w;
        u.h[4] = (f16)b.x; u.h[5] = (f16)b.y; u.h[6] = (f16)b.z; u.h[7] = (f16)b.w;
    } else {
        u.q = (int4){0, 0, 0, 0};
    }
    *(int4*)(Bf + (size_t)c * kKp + k8 * 8) = u.q;
}

// ---------------------------------------------------------------- conv1d -> locPad [M][64] f16 (cols 32..63 zeroed)
__global__ void k_loc(const float* __restrict__ la, const float* __restrict__ cw,
                      const float* __restrict__ cb, f16* __restrict__ locPad) {
    int m = blockIdx.x * 256 + threadIdx.x;          // < kM
    int b = m / kT, t = m - b * kT;
    float x0 = (t > 0)      ? la[(size_t)b * kT + t - 1] : 0.f;
    float x1 = la[(size_t)b * kT + t];
    float x2 = (t < kT - 1) ? la[(size_t)b * kT + t + 1] : 0.f;
    union { f16 h[32]; int4 q[4]; } u;
#pragma unroll
    for (int k = 0; k < 32; ++k)
        u.h[k] = (f16)(cw[k * 3] * x0 + cw[k * 3 + 1] * x1 + cw[k * 3 + 2] * x2 + cb[k]);
    int4* dst = (int4*)(locPad + (size_t)m * 64);
    dst[0] = u.q[0]; dst[1] = u.q[1]; dst[2] = u.q[2]; dst[3] = u.q[3];
    int4 z = {0, 0, 0, 0};
    dst[4] = z; dst[5] = z; dst[6] = z; dst[7] = z;   // zeroed: tail kk=1 reads 0 x 0
}

// ---------------------------------------------------------------- prep add = dec@W^T + bias
__global__ void k_prep_add(const float* __restrict__ dec, const float* __restrict__ W,
                           const float* __restrict__ bias, float* __restrict__ add) {
    __shared__ float dl[kH];
    int bb = blockIdx.x >> 2;
    int cc = (blockIdx.x & 3) * 256 + threadIdx.x;
    *(float4*)&dl[threadIdx.x * 4] = *(const float4*)&dec[(size_t)bb * kH + threadIdx.x * 4];
    __syncthreads();
    float acc = bias[cc];
    const float* wr = W + (size_t)cc * kH;
    for (int h = 0; h < kH; h += 4) {
        float4 wv = *(const float4*)&wr[h];
        acc += wv.x * dl[h] + wv.y * dl[h + 1] + wv.z * dl[h + 2] + wv.w * dl[h + 3];
    }
    add[(size_t)bb * kC + cc] = acc;
}

// ---------------------------------------------------------------- fused main GEMM
// Tile 128(M) x 128(N), BK=64, 256 thr = 4 waves (2M x 2N), per-wave 64x64.
// LDS (34816 B): As f16 [128 rows][8 chunks 16B, phys c ^ (row&7)] @0 (16 KB);
//   Bs f16 @16384 (16 KB); add_l @32768; w_l @33280; sred @33792.
// A: enc f32 reg-staged, write-side cvt (2 thr/row x 8 float4 -> 32 cvt ->
//    4 swizzled ds_write_b128, bank-uniform). B: gload_lds from Bf, uniform
//    +t*64 for t=0..16 (t=16 = U cols + zero pad). Tail A: gload_lds locPad.
// 4 blocks/CU = 4 independent barrier groups (the R12-proven regime).
__launch_bounds__(256, 4)
__global__ void k_main(const float* __restrict__ enc, const f16* __restrict__ Bg,
                       const f16* __restrict__ locPad, const float* __restrict__ add,
                       const float* __restrict__ wvec, float* __restrict__ spart) {
    __shared__ __align__(16) char smem[34816];
    float* add_l = (float*)(smem + 32768);
    float* w_l   = (float*)(smem + 33280);
    float (*sred)[64][2] = (float (*)[64][2])(smem + 33792);

    const int tid = threadIdx.x, lane = tid & 63, wave = tid >> 6;
    const int wm = wave >> 1, wn = wave & 1;
    // bijective XCD swizzle: 3072 blocks = 8 XCDs x 384; nt fastest (8 per A strip)
    const int raw = blockIdx.x;
    const int lin = (raw & 7) * 384 + (raw >> 3);
    const int mt = lin >> 3, nt = lin & 7;
    const int m0 = mt * 128, n0 = nt * 128;
    const int bb = m0 / kT;                          // 128 | 1536

    if (tid < 128) {
        add_l[tid] = add[(size_t)bb * kC + n0 + tid];
        w_l[tid]   = wvec[n0 + tid];
    }

    f32x4 acc[4][4];
#pragma unroll
    for (int i = 0; i < 4; ++i)
#pragma unroll
        for (int j = 0; j < 4; ++j) acc[i][j] = (f32x4){0.f, 0.f, 0.f, 0.f};

    // A staging (write-side cvt): 2 thr/row, 32 f32 each.
    const int ar = tid >> 1, ah = tid & 1;
    const float* aSrc = enc + (size_t)(m0 + ar) * kH + ah * 32;
    char* aw = smem + ar * 128;
    const int axm = ar & 7;

    // B staging (gload_lds): 4 instr/thread; instr j covers rows wave*32+j*8..+8.
    // lane l: row-in-group rG = l>>3, LDS chunk l&7, src chunk = (l&7)^rG.
    const int rG = lane >> 3;
    const int gc = (lane & 7) ^ rG;
    const f16* bS[4];
    const f16* aT[4];                                // tail A from locPad (128B rows)
#pragma unroll
    for (int j = 0; j < 4; ++j) {
        int row = wave * 32 + j * 8 + rG;
        bS[j] = Bg + (size_t)(n0 + row) * kKp + gc * 8;
        aT[j] = locPad + (size_t)(m0 + row) * 64 + gc * 8;
    }
    const unsigned aDst = wave * 4096u;
    const unsigned bDst = 16384u + wave * 4096u;
    const int g = lane >> 4, rl = lane & 15;

    for (int t = 0; t < 16; ++t) {
        // ---- stage: A f32 loads + cvt + swizzled ds_write; B gload_lds
        const float* ap = aSrc + t * 64;
        float4 f0 = *(const float4*)(ap);
        float4 f1 = *(const float4*)(ap + 4);
        float4 f2 = *(const float4*)(ap + 8);
        float4 f3 = *(const float4*)(ap + 12);
        float4 f4 = *(const float4*)(ap + 16);
        float4 f5 = *(const float4*)(ap + 20);
        float4 f6 = *(const float4*)(ap + 24);
        float4 f7 = *(const float4*)(ap + 28);
#pragma unroll
        for (int j = 0; j < 4; ++j) gload16(bS[j] + t * 64, smem + bDst + j * 1024);
        union { f16 h[32]; int4 q[4]; } pk;
        pk.h[0]  = (f16)f0.x; pk.h[1]  = (f16)f0.y; pk.h[2]  = (f16)f0.z; pk.h[3]  = (f16)f0.w;
        pk.h[4]  = (f16)f1.x; pk.h[5]  = (f16)f1.y; pk.h[6]  = (f16)f1.z; pk.h[7]  = (f16)f1.w;
        pk.h[8]  = (f16)f2.x; pk.h[9]  = (f16)f2.y; pk.h[10] = (f16)f2.z; pk.h[11] = (f16)f2.w;
        pk.h[12] = (f16)f3.x; pk.h[13] = (f16)f3.y; pk.h[14] = (f16)f3.z; pk.h[15] = (f16)f3.w;
        pk.h[16] = (f16)f4.x; pk.h[17] = (f16)f4.y; pk.h[18] = (f16)f4.z; pk.h[19] = (f16)f4.w;
        pk.h[20] = (f16)f5.x; pk.h[21] = (f16)f5.y; pk.h[22] = (f16)f5.z; pk.h[23] = (f16)f5.w;
        pk.h[24] = (f16)f6.x; pk.h[25] = (f16)f6.y; pk.h[26] = (f16)f6.z; pk.h[27] = (f16)f6.w;
        pk.h[28] = (f16)f7.x; pk.h[29] = (f16)f7.y; pk.h[30] = (f16)f7.z; pk.h[31] = (f16)f7.w;
#pragma unroll
        for (int j = 0; j < 4; ++j)
            *(int4*)(aw + (((ah * 4 + j) ^ axm) * 16)) = pk.q[j];
        __syncthreads();
        // ---- compute: 2 kk x 16 MFMA
#pragma unroll
        for (int kk = 0; kk < 2; ++kk) {
            f16x8 bfv[4], af[4];
#pragma unroll
            for (int ni = 0; ni < 4; ++ni)
                bfv[ni] = *(const f16x8*)(smem + 16384 + (wn * 64 + ni * 16 + rl) * 128
                                          + (((kk * 4 + g) ^ (rl & 7)) << 4));
#pragma unroll
            for (int mi = 0; mi < 4; ++mi)
                af[mi] = *(const f16x8*)(smem + (wm * 64 + mi * 16 + rl) * 128
                                         + (((kk * 4 + g) ^ (rl & 7)) << 4));
            __builtin_amdgcn_s_setprio(1);
#pragma unroll
            for (int mi = 0; mi < 4; ++mi)
#pragma unroll
                for (int ni = 0; ni < 4; ++ni)
                    acc[mi][ni] = __builtin_amdgcn_mfma_f32_16x16x32_f16(af[mi], bfv[ni], acc[mi][ni], 0, 0, 0);
            __builtin_amdgcn_s_setprio(0);
        }
        __syncthreads();
    }

    // ---- tail K-step (t=16): A from locPad (loc|zeros), B cols 1024..1087 (U|zeros)
    {
#pragma unroll
        for (int j = 0; j < 4; ++j) gload16(aT[j], smem + aDst + j * 1024);
#pragma unroll
        for (int j = 0; j < 4; ++j) gload16(bS[j] + 1024, smem + bDst + j * 1024);
        __syncthreads();
#pragma unroll
        for (int kk = 0; kk < 2; ++kk) {             // kk=1: zeros x zeros = 0
            f16x8 bfv[4], af[4];
#pragma unroll
            for (int ni = 0; ni < 4; ++ni)
                bfv[ni] = *(const f16x8*)(smem + 16384 + (wn * 64 + ni * 16 + rl) * 128
                                          + (((kk * 4 + g) ^ (rl & 7)) << 4));
#pragma unroll
            for (int mi = 0; mi < 4; ++mi)
                af[mi] = *(const f16x8*)(smem + (wm * 64 + mi * 16 + rl) * 128
                                         + (((kk * 4 + g) ^ (rl & 7)) << 4));
            __builtin_amdgcn_s_setprio(1);
#pragma unroll
            for (int mi = 0; mi < 4; ++mi)
#pragma unroll
                for (int ni = 0; ni < 4; ++ni)
                    acc[mi][ni] = __builtin_amdgcn_mfma_f32_16x16x32_f16(af[mi], bfv[ni], acc[mi][ni], 0, 0, 0);
            __builtin_amdgcn_s_setprio(0);
        }
        __syncthreads();
    }

    // ---- epilogue: e = tanh(acc + add[c]); partial score = sum_c e*w[c]
#pragma unroll
    for (int mi = 0; mi < 4; ++mi) {
#pragma unroll
        for (int i = 0; i < 4; ++i) {
            float p = 0.f;
#pragma unroll
            for (int ni = 0; ni < 4; ++ni) {
                int cl = wn * 64 + ni * 16 + rl;
                float e = tanhf(acc[mi][ni][i] + add_l[cl]);
                p += e * w_l[cl];
            }
            p += __shfl_xor(p, 1);
            p += __shfl_xor(p, 2);
            p += __shfl_xor(p, 4);
            p += __shfl_xor(p, 8);
            if (rl == 0) sred[wm][mi * 16 + g * 4 + i][wn] = p;
        }
    }
    __syncthreads();
    if (tid < 128) {
        int r = tid & 63, w2 = tid >> 6;
        float s = sred[w2][r][0] + sred[w2][r][1];
        spart[(size_t)nt * kM + m0 + tid] = s;
    }
}

// ---------------------------------------------------------------- softmax over T (8 partials)
__global__ void k_softmax(const float* __restrict__ spart, float* __restrict__ out_align) {
    __shared__ float red[256];
    int b = blockIdx.x, tid = threadIdx.x;
    float v[6];
    float mx = -1e30f;
#pragma unroll
    for (int i = 0; i < 6; ++i) {
        size_t idx = (size_t)b * kT + tid + i * 256;
        float s = 0.f;
#pragma unroll
        for (int p = 0; p < 8; ++p) s += spart[(size_t)p * kM + idx];
        v[i] = s; mx = fmaxf(mx, s);
    }
    red[tid] = mx; __syncthreads();
    for (int o = 128; o > 0; o >>= 1) { if (tid < o) red[tid] = fmaxf(red[tid], red[tid + o]); __syncthreads(); }
    mx = red[0]; __syncthreads();
    float sum = 0.f;
#pragma unroll
    for (int i = 0; i < 6; ++i) { v[i] = expf(v[i] - mx); sum += v[i]; }
    red[tid] = sum; __syncthreads();
    for (int o = 128; o > 0; o >>= 1) { if (tid < o) red[tid] += red[tid + o]; __syncthreads(); }
    float inv = 1.f / red[0];
#pragma unroll
    for (int i = 0; i < 6; ++i)
        out_align[(size_t)b * kT + tid + i * 256] = v[i] * inv;
}

// ---------------------------------------------------------------- context (enc f32, L3-hot after k_main)
__global__ void k_ctx_part(const float* __restrict__ enc, const float* __restrict__ align,
                           float* __restrict__ cpart) {
    __shared__ float al[192];
    int ci = blockIdx.x, b = blockIdx.y, tid = threadIdx.x;
    if (tid < 192) al[tid] = align[(size_t)b * kT + ci * 192 + tid];
    __syncthreads();
    float4 acc = {0.f, 0.f, 0.f, 0.f};
    const float* ep = enc + ((size_t)b * kT + (size_t)ci * 192) * kH + tid * 4;
    for (int t = 0; t < 192; ++t) {
        float a = al[t];
        float4 e = *(const float4*)(ep + (size_t)t * kH);
        acc.x += a * e.x; acc.y += a * e.y; acc.z += a * e.z; acc.w += a * e.w;
    }
    *(float4*)&cpart[((size_t)ci * kB + b) * kH + tid * 4] = acc;
}

__global__ void k_ctx_red(const float* __restrict__ cpart, float* __restrict__ out_ctx) {
    int idx = blockIdx.x * 256 + threadIdx.x;
    float s = 0.f;
#pragma unroll
    for (int ci = 0; ci < 8; ++ci) s += cpart[(size_t)ci * kB * kH + idx];
    out_ctx[idx] = s;
}

// ---------------------------------------------------------------- launch
extern "C" void kernel_launch(void* const* d_in, const int* in_sizes, int n_in,
                              void* d_out, int out_size, void* d_ws, size_t ws_size,
                              hipStream_t stream) {
    const float* dec  = (const float*)d_in[0];
    const float* enc  = (const float*)d_in[1];
    const float* la   = (const float*)d_in[2];
    const float* W    = (const float*)d_in[3];
    const float* V    = (const float*)d_in[4];
    const float* U    = (const float*)d_in[5];
    const float* bias = (const float*)d_in[6];
    const float* wv   = (const float*)d_in[7];
    const float* cw   = (const float*)d_in[8];
    const float* cb   = (const float*)d_in[9];

    char* ws = (char*)d_ws;
    f16* Bf      = (f16*)(ws + WS_B);
    f16* locPad  = (f16*)(ws + WS_LOC);
    float* add   = (float*)(ws + WS_ADD);
    float* spart = (float*)(ws + WS_SCR);            // 8*kM f32
    float* cpart = (float*)(ws + WS_SCR);            // 8*kB*kH f32 (spart dead post-softmax)

    float* out_ctx   = (float*)d_out;            // (B,H)
    float* out_align = (float*)d_out + kB * kH;  // (B,T)

    hipLaunchKernelGGL(k_prep_b2,  dim3(kC),             dim3(256), 0, stream, V, U, Bf);
    hipLaunchKernelGGL(k_loc,      dim3(kM / 256),       dim3(256), 0, stream, la, cw, cb, locPad);
    hipLaunchKernelGGL(k_prep_add, dim3(kB * 4),         dim3(256), 0, stream, dec, W, bias, add);
    hipLaunchKernelGGL(k_main,     dim3((kM / 128) * 8), dim3(256), 0, stream, enc, Bf, locPad, add, wv, spart);
    hipLaunchKernelGGL(k_softmax,  dim3(kB),             dim3(256), 0, stream, spart, out_align);
    hipLaunchKernelGGL(k_ctx_part, dim3(8, kB),          dim3(256), 0, stream, enc, out_align, cpart);
    hipLaunchKernelGGL(k_ctx_red,  dim3(kB * kH / 256),  dim3(256), 0, stream, cpart, out_ctx);
}

// Round 15
// 325.115 us; speedup vs baseline: 1.0001x; 1.0001x over previous
//
#include <hip/hip_runtime.h>
#include <hip/hip_bf16.h>
#include <hip/hip_fp16.h>

// Bahdanau location-sensitive attention, fused f16-MFMA implementation.
// R15: R12 shell (Af f16 materialization; 128x128 tile, 256 thr, 4 blocks/CU)
//      with B read DIRECTLY from L2 into registers (Bf is 2.2 MB, L2-resident)
//      -> no Bs in LDS: halves LDS reads AND staged writes (k_main was
//      LDS-BW-bound: ~4100 cy LDS vs 1241 cy MFMA per CU-K-step).
//      A stays gload_lds (96 MB Af, needs staging). LDS 18 KB.
// B=32 T=1536 H=1024 CTX=1024 CONV_OUT=32

constexpr int kB = 32, kT = 1536, kH = 1024, kC = 1024, kCO = 32;
constexpr int kM = kB * kT;      // 49152
constexpr int kKp = 1088;        // padded K: 1024 enc | 32 loc | 32 zero

typedef _Float16 f16;
typedef _Float16 f16x8 __attribute__((ext_vector_type(8)));
typedef float f32x4 __attribute__((ext_vector_type(4)));

// ---- ws layout (bytes) ----
constexpr size_t W2_A    = 0;                                    // kM*kKp f16 = 106.95 MB
constexpr size_t W2_B    = W2_A + (size_t)kM * kKp * 2;          // kC*kKp f16 = 2.23 MB
constexpr size_t W2_ADD  = W2_B + (size_t)kC * kKp * 2;          // kB*kC f32
constexpr size_t W2_SCR  = W2_ADD + (size_t)kB * kC * 4;         // spart/cpart aliased

__device__ __forceinline__ void gload16(const void* g, void* l) {
    __builtin_amdgcn_global_load_lds(
        (const __attribute__((address_space(1))) void*)g,
        (__attribute__((address_space(3))) void*)l, 16, 0, 0);
}

// ---------------------------------------------------------------- cvt enc -> Af cols 0..1023 (sequential HBM)
__global__ void k_cvt(const float* __restrict__ enc, f16* __restrict__ Af) {
    int gid = blockIdx.x * 256 + threadIdx.x;       // < kM*kH/8
    int row = gid >> 7, c8 = gid & 127;
    const float* src = enc + (size_t)row * kH + c8 * 8;
    float4 e0 = *(const float4*)src;
    float4 e1 = *(const float4*)(src + 4);
    union { f16 h[8]; int4 q; } u;
    u.h[0] = (f16)e0.x; u.h[1] = (f16)e0.y; u.h[2] = (f16)e0.z; u.h[3] = (f16)e0.w;
    u.h[4] = (f16)e1.x; u.h[5] = (f16)e1.y; u.h[6] = (f16)e1.z; u.h[7] = (f16)e1.w;
    *(int4*)(Af + (size_t)row * kKp + c8 * 8) = u.q;
}

// ---------------------------------------------------------------- conv1d -> Af cols 1024..1087
__global__ void k_loc(const float* __restrict__ la, const float* __restrict__ cw,
                      const float* __restrict__ cb, f16* __restrict__ Af) {
    int m = blockIdx.x * 256 + threadIdx.x;          // < kM
    int b = m / kT, t = m - b * kT;
    float x0 = (t > 0)      ? la[(size_t)b * kT + t - 1] : 0.f;
    float x1 = la[(size_t)b * kT + t];
    float x2 = (t < kT - 1) ? la[(size_t)b * kT + t + 1] : 0.f;
    union { f16 h[32]; int4 q[4]; } u;
#pragma unroll
    for (int k = 0; k < 32; ++k)
        u.h[k] = (f16)(cw[k * 3] * x0 + cw[k * 3 + 1] * x1 + cw[k * 3 + 2] * x2 + cb[k]);
    int4* dst = (int4*)(Af + (size_t)m * kKp + kH);
    dst[0] = u.q[0]; dst[1] = u.q[1]; dst[2] = u.q[2]; dst[3] = u.q[3];
    int4 z = {0, 0, 0, 0};
    dst[4] = z; dst[5] = z; dst[6] = z; dst[7] = z;   // zero pad 1056..1087
}

// ---------------------------------------------------------------- B pack [kC][1088] f16 (vectorized)
__global__ void k_prep_b2(const float* __restrict__ V, const float* __restrict__ U,
                          f16* __restrict__ Bf) {
    int c = blockIdx.x, k8 = threadIdx.x;            // active k8 < 136
    if (k8 >= 136) return;
    union { f16 h[8]; int4 q; } u;
    if (k8 < 128) {
        const float* src = V + (size_t)c * kH + k8 * 8;
        float4 a = *(const float4*)src, b = *(const float4*)(src + 4);
        u.h[0] = (f16)a.x; u.h[1] = (f16)a.y; u.h[2] = (f16)a.z; u.h[3] = (f16)a.w;
        u.h[4] = (f16)b.x; u.h[5] = (f16)b.y; u.h[6] = (f16)b.z; u.h[7] = (f16)b.w;
    } else if (k8 < 132) {
        const float* src = U + (size_t)c * kCO + (k8 - 128) * 8;
        float4 a = *(const float4*)src, b = *(const float4*)(src + 4);
        u.h[0] = (f16)a.x; u.h[1] = (f16)a.y; u.h[2] = (f16)a.z; u.h[3] = (f16)a.w;
        u.h[4] = (f16)b.x; u.h[5] = (f16)b.y; u.h[6] = (f16)b.z; u.h[7] = (f16)b.w;
    } else {
        u.q = (int4){0, 0, 0, 0};
    }
    *(int4*)(Bf + (size_t)c * kKp + k8 * 8) = u.q;
}

// ---------------------------------------------------------------- prep add = dec@W^T + bias
__global__ void k_prep_add(const float* __restrict__ dec, const float* __restrict__ W,
                           const float* __restrict__ bias, float* __restrict__ add) {
    __shared__ float dl[kH];
    int bb = blockIdx.x >> 2;
    int cc = (blockIdx.x & 3) * 256 + threadIdx.x;
    *(float4*)&dl[threadIdx.x * 4] = *(const float4*)&dec[(size_t)bb * kH + threadIdx.x * 4];
    __syncthreads();
    float acc = bias[cc];
    const float* wr = W + (size_t)cc * kH;
    for (int h = 0; h < kH; h += 4) {
        float4 wv = *(const float4*)&wr[h];
        acc += wv.x * dl[h] + wv.y * dl[h + 1] + wv.z * dl[h + 2] + wv.w * dl[h + 3];
    }
    add[(size_t)bb * kC + cc] = acc;
}

// ---------------------------------------------------------------- fused main GEMM
// Tile 128(M) x 128(N), BK=64, 256 thr = 4 waves (2M x 2N), per-wave 64x64.
// LDS (18432 B): As f16 [128 rows][8 chunks 16B, phys c ^ (row&7)] @0 (16 KB);
//   add_l @16384; w_l @16896; sred @17408.
// A: gload_lds from Af (linear dest, source chunk-permuted). B: per-kk direct
//   global f16x8 loads from Bf (L2-resident 2.2 MB) into registers — no Bs,
//   half the LDS reads, half the staged writes, barrier payload = A only.
// 4 blocks/CU (the R12-proven TLP regime).
__launch_bounds__(256, 4)
__global__ void k_main(const f16* __restrict__ Ag, const f16* __restrict__ Bg,
                       const float* __restrict__ add, const float* __restrict__ wvec,
                       float* __restrict__ spart) {
    __shared__ __align__(16) char smem[18432];
    float* add_l = (float*)(smem + 16384);
    float* w_l   = (float*)(smem + 16896);
    float (*sred)[64][2] = (float (*)[64][2])(smem + 17408);

    const int tid = threadIdx.x, lane = tid & 63, wave = tid >> 6;
    const int wm = wave >> 1, wn = wave & 1;
    // bijective XCD swizzle: 3072 blocks = 8 XCDs x 384; nt fastest (8 per A strip)
    const int raw = blockIdx.x;
    const int lin = (raw & 7) * 384 + (raw >> 3);
    const int mt = lin >> 3, nt = lin & 7;
    const int m0 = mt * 128, n0 = nt * 128;
    const int bb = m0 / kT;                          // 128 | 1536

    if (tid < 128) {
        add_l[tid] = add[(size_t)bb * kC + n0 + tid];
        w_l[tid]   = wvec[n0 + tid];
    }

    f32x4 acc[4][4];
#pragma unroll
    for (int i = 0; i < 4; ++i)
#pragma unroll
        for (int j = 0; j < 4; ++j) acc[i][j] = (f32x4){0.f, 0.f, 0.f, 0.f};

    // A staging (gload_lds): instr j covers rows wave*32+j*8..+8; lane l:
    // row-in-group rG = l>>3, LDS chunk l&7, src chunk = (l&7)^rG.
    const int rG = lane >> 3;
    const int gc = (lane & 7) ^ rG;
    const f16* aS[4];
#pragma unroll
    for (int j = 0; j < 4; ++j)
        aS[j] = Ag + (size_t)(m0 + wave * 32 + j * 8 + rG) * kKp + gc * 8;
    const unsigned aDst = wave * 4096u;

    const int g = lane >> 4, rl = lane & 15;
    // B fragment pointers (direct L2): lane reads B^T row (col) = n0+wn*64+ni*16+rl,
    // k-chunk g*8 within each K=32 slice; per (t,kk): + t*64 + kk*32.
    const f16* bP[4];
#pragma unroll
    for (int ni = 0; ni < 4; ++ni)
        bP[ni] = Bg + (size_t)(n0 + wn * 64 + ni * 16 + rl) * kKp + g * 8;

#define KK_STEP(T, KK) {                                                                      \
    f16x8 bfv[4], af[4];                                                                      \
    _Pragma("unroll") for (int ni = 0; ni < 4; ++ni)                                          \
        bfv[ni] = *(const f16x8*)(bP[ni] + (T) * 64 + (KK) * 32);                             \
    _Pragma("unroll") for (int mi = 0; mi < 4; ++mi)                                          \
        af[mi] = *(const f16x8*)(smem + (wm * 64 + mi * 16 + rl) * 128                        \
                                 + ((((KK) * 4 + g) ^ (rl & 7)) << 4));                       \
    __builtin_amdgcn_s_setprio(1);                                                            \
    _Pragma("unroll") for (int mi = 0; mi < 4; ++mi)                                          \
        _Pragma("unroll") for (int ni = 0; ni < 4; ++ni)                                      \
            acc[mi][ni] = __builtin_amdgcn_mfma_f32_16x16x32_f16(af[mi], bfv[ni], acc[mi][ni], 0, 0, 0); \
    __builtin_amdgcn_s_setprio(0); }

    for (int t = 0; t < 16; ++t) {
#pragma unroll
        for (int j = 0; j < 4; ++j) gload16(aS[j] + t * 64, smem + aDst + j * 1024);
        __syncthreads();
        KK_STEP(t, 0)
        KK_STEP(t, 1)
        __syncthreads();
    }
    // tail t=16: A = loc (K=32 real, cols 1024..1055) | B = U; kk=0 only
    {
#pragma unroll
        for (int j = 0; j < 4; ++j) gload16(aS[j] + 1024, smem + aDst + j * 1024);
        __syncthreads();
        KK_STEP(16, 0)
        __syncthreads();
    }
#undef KK_STEP

    // ---- epilogue: e = tanh(acc + add[c]); partial score = sum_c e*w[c]
#pragma unroll
    for (int mi = 0; mi < 4; ++mi) {
#pragma unroll
        for (int i = 0; i < 4; ++i) {
            float p = 0.f;
#pragma unroll
            for (int ni = 0; ni < 4; ++ni) {
                int cl = wn * 64 + ni * 16 + rl;
                float e = tanhf(acc[mi][ni][i] + add_l[cl]);
                p += e * w_l[cl];
            }
            p += __shfl_xor(p, 1);
            p += __shfl_xor(p, 2);
            p += __shfl_xor(p, 4);
            p += __shfl_xor(p, 8);
            if (rl == 0) sred[wm][mi * 16 + g * 4 + i][wn] = p;
        }
    }
    __syncthreads();
    if (tid < 128) {
        int r = tid & 63, w2 = tid >> 6;
        float s = sred[w2][r][0] + sred[w2][r][1];
        spart[(size_t)nt * kM + m0 + tid] = s;
    }
}

// ---------------------------------------------------------------- softmax over T (8 partials)
__global__ void k_softmax(const float* __restrict__ spart, float* __restrict__ out_align) {
    __shared__ float red[256];
    int b = blockIdx.x, tid = threadIdx.x;
    float v[6];
    float mx = -1e30f;
#pragma unroll
    for (int i = 0; i < 6; ++i) {
        size_t idx = (size_t)b * kT + tid + i * 256;
        float s = 0.f;
#pragma unroll
        for (int p = 0; p < 8; ++p) s += spart[(size_t)p * kM + idx];
        v[i] = s; mx = fmaxf(mx, s);
    }
    red[tid] = mx; __syncthreads();
    for (int o = 128; o > 0; o >>= 1) { if (tid < o) red[tid] = fmaxf(red[tid], red[tid + o]); __syncthreads(); }
    mx = red[0]; __syncthreads();
    float sum = 0.f;
#pragma unroll
    for (int i = 0; i < 6; ++i) { v[i] = expf(v[i] - mx); sum += v[i]; }
    red[tid] = sum; __syncthreads();
    for (int o = 128; o > 0; o >>= 1) { if (tid < o) red[tid] += red[tid + o]; __syncthreads(); }
    float inv = 1.f / red[0];
#pragma unroll
    for (int i = 0; i < 6; ++i)
        out_align[(size_t)b * kT + tid + i * 256] = v[i] * inv;
}

// ---------------------------------------------------------------- context (vectorized Af f16x8 reads)
__global__ void k_ctx_part(const f16* __restrict__ Af, const float* __restrict__ align,
                           float* __restrict__ cpart) {
    __shared__ float al[192];
    int ci = blockIdx.x, b = blockIdx.y, tid = threadIdx.x;
    if (tid < 192) al[tid] = align[(size_t)b * kT + ci * 192 + tid];
    __syncthreads();
    const int half = tid >> 7;                        // rows [half*96, +96)
    const int c8 = tid & 127;                         // 8 H-cols
    float a0 = 0.f, a1 = 0.f, a2 = 0.f, a3 = 0.f, a4 = 0.f, a5 = 0.f, a6 = 0.f, a7 = 0.f;
    const f16* ep = Af + ((size_t)b * kT + ci * 192 + half * 96) * kKp + c8 * 8;
    for (int t = 0; t < 96; ++t) {
        float a = al[half * 96 + t];
        f16x8 e = *(const f16x8*)(ep + (size_t)t * kKp);
        a0 += a * (float)e[0]; a1 += a * (float)e[1]; a2 += a * (float)e[2]; a3 += a * (float)e[3];
        a4 += a * (float)e[4]; a5 += a * (float)e[5]; a6 += a * (float)e[6]; a7 += a * (float)e[7];
    }
    size_t base = ((size_t)(ci * 2 + half) * kB + b) * kH + (size_t)c8 * 8;
    *(float4*)&cpart[base]     = (float4){a0, a1, a2, a3};
    *(float4*)&cpart[base + 4] = (float4){a4, a5, a6, a7};
}

__global__ void k_ctx_red(const float* __restrict__ cpart, float* __restrict__ out_ctx) {
    int idx = blockIdx.x * 256 + threadIdx.x;
    float s = 0.f;
#pragma unroll
    for (int p = 0; p < 16; ++p) s += cpart[(size_t)p * kB * kH + idx];
    out_ctx[idx] = s;
}

// ---------------------------------------------------------------- launch
extern "C" void kernel_launch(void* const* d_in, const int* in_sizes, int n_in,
                              void* d_out, int out_size, void* d_ws, size_t ws_size,
                              hipStream_t stream) {
    const float* dec  = (const float*)d_in[0];
    const float* enc  = (const float*)d_in[1];
    const float* la   = (const float*)d_in[2];
    const float* W    = (const float*)d_in[3];
    const float* V    = (const float*)d_in[4];
    const float* U    = (const float*)d_in[5];
    const float* bias = (const float*)d_in[6];
    const float* wv   = (const float*)d_in[7];
    const float* cw   = (const float*)d_in[8];
    const float* cb   = (const float*)d_in[9];

    char* ws = (char*)d_ws;
    f16* Af      = (f16*)(ws + W2_A);
    f16* Bf      = (f16*)(ws + W2_B);
    float* add   = (float*)(ws + W2_ADD);
    float* spart = (float*)(ws + W2_SCR);            // 8*kM f32
    float* cpart = (float*)(ws + W2_SCR);            // 16*kB*kH f32 (spart dead post-softmax)

    float* out_ctx   = (float*)d_out;            // (B,H)
    float* out_align = (float*)d_out + kB * kH;  // (B,T)

    hipLaunchKernelGGL(k_prep_b2,  dim3(kC),             dim3(256), 0, stream, V, U, Bf);
    hipLaunchKernelGGL(k_loc,      dim3(kM / 256),       dim3(256), 0, stream, la, cw, cb, Af);
    hipLaunchKernelGGL(k_cvt,      dim3(kM * kH / 8 / 256), dim3(256), 0, stream, enc, Af);
    hipLaunchKernelGGL(k_prep_add, dim3(kB * 4),         dim3(256), 0, stream, dec, W, bias, add);
    hipLaunchKernelGGL(k_main,     dim3((kM / 128) * 8), dim3(256), 0, stream, Af, Bf, add, wv, spart);
    hipLaunchKernelGGL(k_softmax,  dim3(kB),             dim3(256), 0, stream, spart, out_align);
    hipLaunchKernelGGL(k_ctx_part, dim3(8, kB),          dim3(256), 0, stream, Af, out_align, cpart);
    hipLaunchKernelGGL(k_ctx_red,  dim3(kB * kH / 256),  dim3(256), 0, stream, cpart, out_ctx);
}

// Round 16
// 225.327 us; speedup vs baseline: 1.4430x; 1.4429x over previous
//
#include <hip/hip_runtime.h>
#include <hip/hip_bf16.h>
#include <hip/hip_fp16.h>

// Bahdanau location-sensitive attention, fused f16-MFMA implementation.
// R16 (consolidation): R9 architecture — k_main reads enc f32 directly with
//   write-side f32->f16 cvt into 16KB f16 As; B via global_load_lds from
//   Bf[kC][1088]; 128x256 tile, 512 thr, 2 blocks/CU; support ~7us (enc stays
//   L3-hot for ctx_part). Best measured total of all 15 prior variants (212us).
// Tweaks vs R9 (zero register cost): B gloads issued BEFORE the A f32 load
//   chain (full-stage latency cover), setprio around MFMA, vectorized prep_b2.
// B=32 T=1536 H=1024 CTX=1024 CONV_OUT=32

constexpr int kB = 32, kT = 1536, kH = 1024, kC = 1024, kCO = 32;
constexpr int kM = kB * kT;      // 49152
constexpr int kKb = 1088;        // padded B K: 1024 V | 32 U | 32 zero

typedef _Float16 f16;
typedef _Float16 f16x8 __attribute__((ext_vector_type(8)));
typedef float f32x4 __attribute__((ext_vector_type(4)));

// ---- ws layout (bytes) ----
constexpr size_t WS_B     = 0;                                   // kC*kKb f16  (2.2 MB)
constexpr size_t WS_LOC   = WS_B + (size_t)kC * kKb * 2;         // kM*64 f16   (6.3 MB)
constexpr size_t WS_ADD   = WS_LOC + (size_t)kM * 64 * 2;        // kB*kC f32
constexpr size_t WS_SCORE = WS_ADD + (size_t)kB * kC * 4;        // 4*kM f32
constexpr size_t WS_CTXP  = WS_SCORE + (size_t)4 * kM * 4;       // 8*kB*kH f32

__device__ __forceinline__ void gload16(const void* g, void* l) {
    __builtin_amdgcn_global_load_lds(
        (const __attribute__((address_space(1))) void*)g,
        (__attribute__((address_space(3))) void*)l, 16, 0, 0);
}

// ---------------------------------------------------------------- B pack [kC][1088] f16 (vectorized)
__global__ void k_prep_b2(const float* __restrict__ V, const float* __restrict__ U,
                          f16* __restrict__ Bf) {
    int c = blockIdx.x, k8 = threadIdx.x;            // active k8 < 136
    if (k8 >= 136) return;
    union { f16 h[8]; int4 q; } u;
    if (k8 < 128) {
        const float* src = V + (size_t)c * kH + k8 * 8;
        float4 a = *(const float4*)src, b = *(const float4*)(src + 4);
        u.h[0] = (f16)a.x; u.h[1] = (f16)a.y; u.h[2] = (f16)a.z; u.h[3] = (f16)a.w;
        u.h[4] = (f16)b.x; u.h[5] = (f16)b.y; u.h[6] = (f16)b.z; u.h[7] = (f16)b.w;
    } else if (k8 < 132) {
        const float* src = U + (size_t)c * kCO + (k8 - 128) * 8;
        float4 a = *(const float4*)src, b = *(const float4*)(src + 4);
        u.h[0] = (f16)a.x; u.h[1] = (f16)a.y; u.h[2] = (f16)a.z; u.h[3] = (f16)a.w;
        u.h[4] = (f16)b.x; u.h[5] = (f16)b.y; u.h[6] = (f16)b.z; u.h[7] = (f16)b.w;
    } else {
        u.q = (int4){0, 0, 0, 0};
    }
    *(int4*)(Bf + (size_t)c * kKb + k8 * 8) = u.q;
}

// ---------------------------------------------------------------- conv1d -> locPad [M][64] f16 (cols 32..63 zeroed)
__global__ void k_loc(const float* __restrict__ la, const float* __restrict__ cw,
                      const float* __restrict__ cb, f16* __restrict__ locPad) {
    int m = blockIdx.x * 256 + threadIdx.x;          // < kM
    int b = m / kT, t = m - b * kT;
    float x0 = (t > 0)      ? la[(size_t)b * kT + t - 1] : 0.f;
    float x1 = la[(size_t)b * kT + t];
    float x2 = (t < kT - 1) ? la[(size_t)b * kT + t + 1] : 0.f;
    union { f16 h[32]; int4 q[4]; } u;
#pragma unroll
    for (int k = 0; k < 32; ++k)
        u.h[k] = (f16)(cw[k * 3] * x0 + cw[k * 3 + 1] * x1 + cw[k * 3 + 2] * x2 + cb[k]);
    int4* dst = (int4*)(locPad + (size_t)m * 64);
    dst[0] = u.q[0]; dst[1] = u.q[1]; dst[2] = u.q[2]; dst[3] = u.q[3];
    int4 z = {0, 0, 0, 0};
    dst[4] = z; dst[5] = z; dst[6] = z; dst[7] = z;   // staged in tail but never read
}

// ---------------------------------------------------------------- prep add = dec@W^T + bias
__global__ void k_prep_add(const float* __restrict__ dec, const float* __restrict__ W,
                           const float* __restrict__ bias, float* __restrict__ add) {
    __shared__ float dl[kH];
    int bb = blockIdx.x >> 2;
    int cc = (blockIdx.x & 3) * 256 + threadIdx.x;
    *(float4*)&dl[threadIdx.x * 4] = *(const float4*)&dec[(size_t)bb * kH + threadIdx.x * 4];
    __syncthreads();
    float acc = bias[cc];
    const float* wr = W + (size_t)cc * kH;
    for (int h = 0; h < kH; h += 4) {
        float4 wv = *(const float4*)&wr[h];
        acc += wv.x * dl[h] + wv.y * dl[h + 1] + wv.z * dl[h + 2] + wv.w * dl[h + 3];
    }
    add[(size_t)bb * kC + cc] = acc;
}

// ---------------------------------------------------------------- fused main GEMM
// Tile 128(M) x 256(N), BK=64, 512 thr = 8 waves (2M x 4N), per-wave 64x64.
// LDS (53248 B): As f16 [128 rows][8 chunks 16B, XOR row&7] @0 (16 KB);
//   Bs f16 [256 rows][8 chunks, XOR row&7] @16384 (32 KB); add_l @49152;
//   w_l @50176; sred @51200. Simple 2-barrier loop (compiler schedules waits).
// 2 blocks/CU: cross-block TLP hides the per-block stage drains.
// Register budget: 64 VGPR + 64 AGPR = exactly 128/wave at (512,4) — do NOT
// add live-across-compute registers (R11 lesson: spill = 5x).
__launch_bounds__(512, 4)
__global__ void k_main(const float* __restrict__ enc, const f16* __restrict__ Bf,
                       const f16* __restrict__ locPad, const float* __restrict__ add,
                       const float* __restrict__ wvec, float* __restrict__ spart) {
    __shared__ __align__(16) char smem[53248];
    float* add_l = (float*)(smem + 49152);
    float* w_l   = (float*)(smem + 50176);
    float (*sred)[64][4] = (float (*)[64][4])(smem + 51200);

    const int tid = threadIdx.x, lane = tid & 63, wave = tid >> 6;
    const int wm = wave >> 2, wn = wave & 3;
    // bijective XCD swizzle: 1536 blocks = 8 XCDs x 192; 4 consecutive share an A strip
    const int raw = blockIdx.x;
    const int lin = (raw & 7) * 192 + (raw >> 3);
    const int mt = lin >> 2, nt = lin & 3;
    const int m0 = mt * 128, n0 = nt * 256;
    const int bb = m0 / kT;                          // 128 | 1536

    if (tid < 256) {
        add_l[tid] = add[(size_t)bb * kC + n0 + tid];
        w_l[tid]   = wvec[n0 + tid];
    }

    f32x4 acc[4][4];
#pragma unroll
    for (int i = 0; i < 4; ++i)
#pragma unroll
        for (int j = 0; j < 4; ++j) acc[i][j] = (f32x4){0.f, 0.f, 0.f, 0.f};

    // A staging (write-side cvt): 4 thr/row, 16 f32 each -> 2 swizzled ds_write_b128
    const int ar = tid >> 2, aq = tid & 3;
    const float* aSrc = enc + (size_t)(m0 + ar) * kH + aq * 16;
    char* aw = smem + ar * 128;
    const int axm = ar & 7;

    // B staging (gload_lds): 4 instr/wave, each 8 rows x 128B; linear dest,
    // inverse-swizzled source chunk gcB = (lane&7) ^ (row&7).
    const int rB = lane >> 3;
    const int gcB = (lane & 7) ^ rB;
    const f16* bSrc[4];
#pragma unroll
    for (int j = 0; j < 4; ++j)
        bSrc[j] = Bf + (size_t)(n0 + wave * 32 + j * 8 + rB) * kKb + gcB * 8;
    const unsigned bDst = 16384u + wave * 4096u;

    const int g = lane >> 4, rl = lane & 15;

    for (int t = 0; t < 16; ++t) {
        // ---- stage: B gloads FIRST (full-stage latency cover), then A f32
        //      loads + cvt + pack + swizzled ds_write
#pragma unroll
        for (int j = 0; j < 4; ++j) gload16(bSrc[j] + t * 64, smem + bDst + j * 1024);
        const float* ap = aSrc + t * 64;
        float4 f0 = *(const float4*)(ap);
        float4 f1 = *(const float4*)(ap + 4);
        float4 f2 = *(const float4*)(ap + 8);
        float4 f3 = *(const float4*)(ap + 12);
        union { f16 h[16]; int4 q[2]; } pk;
        pk.h[0] = (f16)f0.x;  pk.h[1] = (f16)f0.y;  pk.h[2] = (f16)f0.z;  pk.h[3] = (f16)f0.w;
        pk.h[4] = (f16)f1.x;  pk.h[5] = (f16)f1.y;  pk.h[6] = (f16)f1.z;  pk.h[7] = (f16)f1.w;
        pk.h[8] = (f16)f2.x;  pk.h[9] = (f16)f2.y;  pk.h[10] = (f16)f2.z; pk.h[11] = (f16)f2.w;
        pk.h[12] = (f16)f3.x; pk.h[13] = (f16)f3.y; pk.h[14] = (f16)f3.z; pk.h[15] = (f16)f3.w;
        *(int4*)(aw + (((aq * 2 + 0) ^ axm) * 16)) = pk.q[0];
        *(int4*)(aw + (((aq * 2 + 1) ^ axm) * 16)) = pk.q[1];
        __syncthreads();
        // ---- compute: 2 kk x 16 MFMA (compiler-scheduled lgkm)
#pragma unroll
        for (int kk = 0; kk < 2; ++kk) {
            f16x8 bfv[4], af[4];
#pragma unroll
            for (int ni = 0; ni < 4; ++ni)
                bfv[ni] = *(const f16x8*)(smem + 16384 + (wn * 64 + ni * 16 + rl) * 128
                                          + (((kk * 4 + g) ^ (rl & 7)) << 4));
#pragma unroll
            for (int mi = 0; mi < 4; ++mi)
                af[mi] = *(const f16x8*)(smem + (wm * 64 + mi * 16 + rl) * 128
                                         + (((kk * 4 + g) ^ (rl & 7)) << 4));
            __builtin_amdgcn_s_setprio(1);
#pragma unroll
            for (int mi = 0; mi < 4; ++mi)
#pragma unroll
                for (int ni = 0; ni < 4; ++ni)
                    acc[mi][ni] = __builtin_amdgcn_mfma_f32_16x16x32_f16(af[mi], bfv[ni], acc[mi][ni], 0, 0, 0);
            __builtin_amdgcn_s_setprio(0);
        }
        __syncthreads();
    }

    // ---- tail: loc @ U^T, K=32 (A rows from locPad f16; B cols 1024.. incl zero pad)
    {
        const f16* tS0 = locPad + (size_t)(m0 + wave * 16 + 0 + rB) * 64 + gcB * 8;
        const f16* tS1 = locPad + (size_t)(m0 + wave * 16 + 8 + rB) * 64 + gcB * 8;
        gload16(tS0, smem + wave * 2048u);
        gload16(tS1, smem + wave * 2048u + 1024u);
#pragma unroll
        for (int j = 0; j < 4; ++j) gload16(bSrc[j] + 1024, smem + bDst + j * 1024);
        __syncthreads();
        f16x8 bfv[4], af[4];
#pragma unroll
        for (int ni = 0; ni < 4; ++ni)
            bfv[ni] = *(const f16x8*)(smem + 16384 + (wn * 64 + ni * 16 + rl) * 128
                                      + ((g ^ (rl & 7)) << 4));
#pragma unroll
        for (int mi = 0; mi < 4; ++mi)
            af[mi] = *(const f16x8*)(smem + (wm * 64 + mi * 16 + rl) * 128
                                     + ((g ^ (rl & 7)) << 4));
        __builtin_amdgcn_s_setprio(1);
#pragma unroll
        for (int mi = 0; mi < 4; ++mi)
#pragma unroll
            for (int ni = 0; ni < 4; ++ni)
                acc[mi][ni] = __builtin_amdgcn_mfma_f32_16x16x32_f16(af[mi], bfv[ni], acc[mi][ni], 0, 0, 0);
        __builtin_amdgcn_s_setprio(0);
        __syncthreads();
    }

    // ---- epilogue: e = tanh(acc + add[c]); partial score = sum_c e*w[c]
#pragma unroll
    for (int mi = 0; mi < 4; ++mi) {
#pragma unroll
        for (int i = 0; i < 4; ++i) {
            float p = 0.f;
#pragma unroll
            for (int ni = 0; ni < 4; ++ni) {
                int cl = wn * 64 + ni * 16 + rl;
                float e = tanhf(acc[mi][ni][i] + add_l[cl]);
                p += e * w_l[cl];
            }
            p += __shfl_xor(p, 1);
            p += __shfl_xor(p, 2);
            p += __shfl_xor(p, 4);
            p += __shfl_xor(p, 8);
            if (rl == 0) sred[wm][mi * 16 + g * 4 + i][wn] = p;
        }
    }
    __syncthreads();
    if (tid < 128) {
        int r = tid & 63, w2 = tid >> 6;
        float s = sred[w2][r][0] + sred[w2][r][1] + sred[w2][r][2] + sred[w2][r][3];
        spart[(size_t)nt * kM + m0 + tid] = s;
    }
}

// ---------------------------------------------------------------- softmax over T (4 partials)
__global__ void k_softmax(const float* __restrict__ spart, float* __restrict__ out_align) {
    __shared__ float red[256];
    int b = blockIdx.x, tid = threadIdx.x;
    float v[6];
    float mx = -1e30f;
#pragma unroll
    for (int i = 0; i < 6; ++i) {
        size_t idx = (size_t)b * kT + tid + i * 256;
        float s = spart[idx] + spart[kM + idx] + spart[2 * (size_t)kM + idx] + spart[3 * (size_t)kM + idx];
        v[i] = s; mx = fmaxf(mx, s);
    }
    red[tid] = mx; __syncthreads();
    for (int o = 128; o > 0; o >>= 1) { if (tid < o) red[tid] = fmaxf(red[tid], red[tid + o]); __syncthreads(); }
    mx = red[0]; __syncthreads();
    float sum = 0.f;
#pragma unroll
    for (int i = 0; i < 6; ++i) { v[i] = expf(v[i] - mx); sum += v[i]; }
    red[tid] = sum; __syncthreads();
    for (int o = 128; o > 0; o >>= 1) { if (tid < o) red[tid] += red[tid + o]; __syncthreads(); }
    float inv = 1.f / red[0];
#pragma unroll
    for (int i = 0; i < 6; ++i)
        out_align[(size_t)b * kT + tid + i * 256] = v[i] * inv;
}

// ---------------------------------------------------------------- context (enc f32, L3-hot after k_main)
__global__ void k_ctx_part(const float* __restrict__ enc, const float* __restrict__ align,
                           float* __restrict__ cpart) {
    __shared__ float al[192];
    int ci = blockIdx.x, b = blockIdx.y, tid = threadIdx.x;
    if (tid < 192) al[tid] = align[(size_t)b * kT + ci * 192 + tid];
    __syncthreads();
    float4 acc = {0.f, 0.f, 0.f, 0.f};
    const float* ep = enc + ((size_t)b * kT + (size_t)ci * 192) * kH + tid * 4;
    for (int t = 0; t < 192; ++t) {
        float a = al[t];
        float4 e = *(const float4*)(ep + (size_t)t * kH);
        acc.x += a * e.x; acc.y += a * e.y; acc.z += a * e.z; acc.w += a * e.w;
    }
    *(float4*)&cpart[((size_t)ci * kB + b) * kH + tid * 4] = acc;
}

__global__ void k_ctx_red(const float* __restrict__ cpart, float* __restrict__ out_ctx) {
    int idx = blockIdx.x * 256 + threadIdx.x;
    float s = 0.f;
#pragma unroll
    for (int ci = 0; ci < 8; ++ci) s += cpart[(size_t)ci * kB * kH + idx];
    out_ctx[idx] = s;
}

// ---------------------------------------------------------------- launch
extern "C" void kernel_launch(void* const* d_in, const int* in_sizes, int n_in,
                              void* d_out, int out_size, void* d_ws, size_t ws_size,
                              hipStream_t stream) {
    const float* dec  = (const float*)d_in[0];
    const float* enc  = (const float*)d_in[1];
    const float* la   = (const float*)d_in[2];
    const float* W    = (const float*)d_in[3];
    const float* V    = (const float*)d_in[4];
    const float* U    = (const float*)d_in[5];
    const float* bias = (const float*)d_in[6];
    const float* wv   = (const float*)d_in[7];
    const float* cw   = (const float*)d_in[8];
    const float* cb   = (const float*)d_in[9];

    char* ws = (char*)d_ws;
    f16* Bf      = (f16*)(ws + WS_B);
    f16* locPad  = (f16*)(ws + WS_LOC);
    float* add   = (float*)(ws + WS_ADD);
    float* spart = (float*)(ws + WS_SCORE);
    float* cpart = (float*)(ws + WS_CTXP);

    float* out_ctx   = (float*)d_out;            // (B,H)
    float* out_align = (float*)d_out + kB * kH;  // (B,T)

    hipLaunchKernelGGL(k_prep_b2,  dim3(kC),            dim3(256), 0, stream, V, U, Bf);
    hipLaunchKernelGGL(k_loc,      dim3(kM / 256),      dim3(256), 0, stream, la, cw, cb, locPad);
    hipLaunchKernelGGL(k_prep_add, dim3(kB * 4),        dim3(256), 0, stream, dec, W, bias, add);
    hipLaunchKernelGGL(k_main,     dim3((kM / 128) * 4), dim3(512), 0, stream, enc, Bf, locPad, add, wv, spart);
    hipLaunchKernelGGL(k_softmax,  dim3(kB),            dim3(256), 0, stream, spart, out_align);
    hipLaunchKernelGGL(k_ctx_part, dim3(8, kB),         dim3(256), 0, stream, enc, out_align, cpart);
    hipLaunchKernelGGL(k_ctx_red,  dim3(kB * kH / 256), dim3(256), 0, stream, cpart, out_ctx);
}

// Round 17
// 212.131 us; speedup vs baseline: 1.5328x; 1.0622x over previous
//
#include <hip/hip_runtime.h>
#include <hip/hip_bf16.h>
#include <hip/hip_fp16.h>

// Bahdanau location-sensitive attention, fused f16-MFMA implementation.
// R17 = R9 verbatim (measured session best: 212.1 us total).
// k_main: 128x256 tile, 512 thr / 8 waves, BK=64, single-buffered 2-barrier
//   loop, 2 blocks/CU. A: enc f32 read in-kernel, write-side f32->f16 cvt into
//   16KB f16 As (4 thr/row x 16 f32 -> 2 swizzled ds_write_b128). B: f16 via
//   global_load_lds from Bf[kC][1088] (linear dest, inverse-swizzled source).
//   Tail K=32: loc @ U^T from locPad. Support ~7us: enc stays L3-hot so
//   ctx_part reads it nearly free; no Af materialization (saves 47us k_cvt).
// Post-R9 exploration summary (all regressed or null): Af+4x256thr blocks
//   (239), BK=32 dbuf (254), in-main f32 at 4 blocks (325), B-direct-L2 (325),
//   B-first+setprio tweaks (225). R11 lesson: (512,6) spills acc -> 5x.
// B=32 T=1536 H=1024 CTX=1024 CONV_OUT=32

constexpr int kB = 32, kT = 1536, kH = 1024, kC = 1024, kCO = 32;
constexpr int kM = kB * kT;      // 49152
constexpr int kKb = 1088;        // padded B K: 1024 V | 32 U | 32 zero

typedef _Float16 f16;
typedef _Float16 f16x8 __attribute__((ext_vector_type(8)));
typedef float f32x4 __attribute__((ext_vector_type(4)));

// ---- ws layout (bytes) ----
constexpr size_t WS_B     = 0;                                   // kC*kKb f16  (2.2 MB)
constexpr size_t WS_LOC   = WS_B + (size_t)kC * kKb * 2;         // kM*64 f16   (6.3 MB)
constexpr size_t WS_ADD   = WS_LOC + (size_t)kM * 64 * 2;        // kB*kC f32
constexpr size_t WS_SCORE = WS_ADD + (size_t)kB * kC * 4;        // 4*kM f32
constexpr size_t WS_CTXP  = WS_SCORE + (size_t)4 * kM * 4;       // 8*kB*kH f32

__device__ __forceinline__ void gload16(const void* g, void* l) {
    __builtin_amdgcn_global_load_lds(
        (const __attribute__((address_space(1))) void*)g,
        (__attribute__((address_space(3))) void*)l, 16, 0, 0);
}

// ---------------------------------------------------------------- B pack [kC][1088] f16
__global__ void k_prep_b2(const float* __restrict__ V, const float* __restrict__ U,
                          f16* __restrict__ Bf) {
    int c = blockIdx.x;
    for (int k = threadIdx.x; k < kKb; k += 256) {
        float v = (k < kH) ? V[(size_t)c * kH + k]
                : (k < kH + kCO) ? U[(size_t)c * kCO + (k - kH)] : 0.f;
        Bf[(size_t)c * kKb + k] = (f16)v;
    }
}

// ---------------------------------------------------------------- conv1d -> locPad [M][64] f16 (cols 0..31)
__global__ void k_loc(const float* __restrict__ la, const float* __restrict__ cw,
                      const float* __restrict__ cb, f16* __restrict__ locPad) {
    int m = blockIdx.x * 256 + threadIdx.x;          // < kM
    int b = m / kT, t = m - b * kT;
    float x0 = (t > 0)      ? la[(size_t)b * kT + t - 1] : 0.f;
    float x1 = la[(size_t)b * kT + t];
    float x2 = (t < kT - 1) ? la[(size_t)b * kT + t + 1] : 0.f;
    union { f16 h[32]; int4 q[4]; } u;
#pragma unroll
    for (int k = 0; k < 32; ++k)
        u.h[k] = (f16)(cw[k * 3] * x0 + cw[k * 3 + 1] * x1 + cw[k * 3 + 2] * x2 + cb[k]);
    int4* dst = (int4*)(locPad + (size_t)m * 64);
    dst[0] = u.q[0]; dst[1] = u.q[1]; dst[2] = u.q[2]; dst[3] = u.q[3];
    // cols 32..63: staged to LDS in the tail but never ds_read
}

// ---------------------------------------------------------------- prep add = dec@W^T + bias
__global__ void k_prep_add(const float* __restrict__ dec, const float* __restrict__ W,
                           const float* __restrict__ bias, float* __restrict__ add) {
    __shared__ float dl[kH];
    int bb = blockIdx.x >> 2;
    int cc = (blockIdx.x & 3) * 256 + threadIdx.x;
    *(float4*)&dl[threadIdx.x * 4] = *(const float4*)&dec[(size_t)bb * kH + threadIdx.x * 4];
    __syncthreads();
    float acc = bias[cc];
    const float* wr = W + (size_t)cc * kH;
    for (int h = 0; h < kH; h += 4) {
        float4 wv = *(const float4*)&wr[h];
        acc += wv.x * dl[h] + wv.y * dl[h + 1] + wv.z * dl[h + 2] + wv.w * dl[h + 3];
    }
    add[(size_t)bb * kC + cc] = acc;
}

// ---------------------------------------------------------------- fused main GEMM
// Tile 128(M) x 256(N), BK=64, 512 thr = 8 waves (2M x 4N), per-wave 64x64.
// LDS (53248 B): As f16 [128 rows][8 chunks 16B, XOR row&7] @0 (16 KB);
//   Bs f16 [256 rows][8 chunks, XOR row&7] @16384 (32 KB); add_l @49152;
//   w_l @50176; sred @51200. Simple 2-barrier loop (m97 regime: compiler
//   schedules waits). 2 blocks/CU -> cross-block TLP hides stage drains.
__launch_bounds__(512, 4)
__global__ void k_main(const float* __restrict__ enc, const f16* __restrict__ Bf,
                       const f16* __restrict__ locPad, const float* __restrict__ add,
                       const float* __restrict__ wvec, float* __restrict__ spart) {
    __shared__ __align__(16) char smem[53248];
    float* add_l = (float*)(smem + 49152);
    float* w_l   = (float*)(smem + 50176);
    float (*sred)[64][4] = (float (*)[64][4])(smem + 51200);

    const int tid = threadIdx.x, lane = tid & 63, wave = tid >> 6;
    const int wm = wave >> 2, wn = wave & 3;
    // bijective XCD swizzle: 1536 blocks = 8 XCDs x 192; 4 consecutive share an A strip
    const int raw = blockIdx.x;
    const int lin = (raw & 7) * 192 + (raw >> 3);
    const int mt = lin >> 2, nt = lin & 3;
    const int m0 = mt * 128, n0 = nt * 256;
    const int bb = m0 / kT;                          // 128 | 1536

    if (tid < 256) {
        add_l[tid] = add[(size_t)bb * kC + n0 + tid];
        w_l[tid]   = wvec[n0 + tid];
    }

    f32x4 acc[4][4];
#pragma unroll
    for (int i = 0; i < 4; ++i)
#pragma unroll
        for (int j = 0; j < 4; ++j) acc[i][j] = (f32x4){0.f, 0.f, 0.f, 0.f};

    // A staging (write-side cvt): 4 thr/row, 16 f32 each -> 2 swizzled ds_write_b128
    const int ar = tid >> 2, aq = tid & 3;
    const float* aSrc = enc + (size_t)(m0 + ar) * kH + aq * 16;
    char* aw = smem + ar * 128;
    const int axm = ar & 7;

    // B staging (gload_lds): 4 instr/wave, each 8 rows x 128B; linear dest,
    // inverse-swizzled source chunk gcB = (lane&7) ^ (row&7).
    const int rB = lane >> 3;
    const int gcB = (lane & 7) ^ rB;
    const f16* bSrc[4];
#pragma unroll
    for (int j = 0; j < 4; ++j)
        bSrc[j] = Bf + (size_t)(n0 + wave * 32 + j * 8 + rB) * kKb + gcB * 8;
    const unsigned bDst = 16384u + wave * 4096u;

    const int g = lane >> 4, rl = lane & 15;

    for (int t = 0; t < 16; ++t) {
        // ---- stage: A f32 loads first (longest chain), B gloads, cvt+write
        const float* ap = aSrc + t * 64;
        float4 f0 = *(const float4*)(ap);
        float4 f1 = *(const float4*)(ap + 4);
        float4 f2 = *(const float4*)(ap + 8);
        float4 f3 = *(const float4*)(ap + 12);
#pragma unroll
        for (int j = 0; j < 4; ++j) gload16(bSrc[j] + t * 64, smem + bDst + j * 1024);
        union { f16 h[16]; int4 q[2]; } pk;
        pk.h[0] = (f16)f0.x;  pk.h[1] = (f16)f0.y;  pk.h[2] = (f16)f0.z;  pk.h[3] = (f16)f0.w;
        pk.h[4] = (f16)f1.x;  pk.h[5] = (f16)f1.y;  pk.h[6] = (f16)f1.z;  pk.h[7] = (f16)f1.w;
        pk.h[8] = (f16)f2.x;  pk.h[9] = (f16)f2.y;  pk.h[10] = (f16)f2.z; pk.h[11] = (f16)f2.w;
        pk.h[12] = (f16)f3.x; pk.h[13] = (f16)f3.y; pk.h[14] = (f16)f3.z; pk.h[15] = (f16)f3.w;
        *(int4*)(aw + (((aq * 2 + 0) ^ axm) * 16)) = pk.q[0];
        *(int4*)(aw + (((aq * 2 + 1) ^ axm) * 16)) = pk.q[1];
        __syncthreads();
        // ---- compute: 2 kk x 16 MFMA (compiler-scheduled lgkm)
#pragma unroll
        for (int kk = 0; kk < 2; ++kk) {
            f16x8 bfv[4], af[4];
#pragma unroll
            for (int ni = 0; ni < 4; ++ni)
                bfv[ni] = *(const f16x8*)(smem + 16384 + (wn * 64 + ni * 16 + rl) * 128
                                          + (((kk * 4 + g) ^ (rl & 7)) << 4));
#pragma unroll
            for (int mi = 0; mi < 4; ++mi)
                af[mi] = *(const f16x8*)(smem + (wm * 64 + mi * 16 + rl) * 128
                                         + (((kk * 4 + g) ^ (rl & 7)) << 4));
#pragma unroll
            for (int mi = 0; mi < 4; ++mi)
#pragma unroll
                for (int ni = 0; ni < 4; ++ni)
                    acc[mi][ni] = __builtin_amdgcn_mfma_f32_16x16x32_f16(af[mi], bfv[ni], acc[mi][ni], 0, 0, 0);
        }
        __syncthreads();
    }

    // ---- tail: loc @ U^T, K=32 (A rows from locPad f16; B cols 1024.. incl zero pad)
    {
        const f16* tS0 = locPad + (size_t)(m0 + wave * 16 + 0 + rB) * 64 + gcB * 8;
        const f16* tS1 = locPad + (size_t)(m0 + wave * 16 + 8 + rB) * 64 + gcB * 8;
        gload16(tS0, smem + wave * 2048u);
        gload16(tS1, smem + wave * 2048u + 1024u);
#pragma unroll
        for (int j = 0; j < 4; ++j) gload16(bSrc[j] + 1024, smem + bDst + j * 1024);
        __syncthreads();
        f16x8 bfv[4], af[4];
#pragma unroll
        for (int ni = 0; ni < 4; ++ni)
            bfv[ni] = *(const f16x8*)(smem + 16384 + (wn * 64 + ni * 16 + rl) * 128
                                      + ((g ^ (rl & 7)) << 4));
#pragma unroll
        for (int mi = 0; mi < 4; ++mi)
            af[mi] = *(const f16x8*)(smem + (wm * 64 + mi * 16 + rl) * 128
                                     + ((g ^ (rl & 7)) << 4));
#pragma unroll
        for (int mi = 0; mi < 4; ++mi)
#pragma unroll
            for (int ni = 0; ni < 4; ++ni)
                acc[mi][ni] = __builtin_amdgcn_mfma_f32_16x16x32_f16(af[mi], bfv[ni], acc[mi][ni], 0, 0, 0);
        __syncthreads();
    }

    // ---- epilogue: e = tanh(acc + add[c]); partial score = sum_c e*w[c]
#pragma unroll
    for (int mi = 0; mi < 4; ++mi) {
#pragma unroll
        for (int i = 0; i < 4; ++i) {
            float p = 0.f;
#pragma unroll
            for (int ni = 0; ni < 4; ++ni) {
                int cl = wn * 64 + ni * 16 + rl;
                float e = tanhf(acc[mi][ni][i] + add_l[cl]);
                p += e * w_l[cl];
            }
            p += __shfl_xor(p, 1);
            p += __shfl_xor(p, 2);
            p += __shfl_xor(p, 4);
            p += __shfl_xor(p, 8);
            if (rl == 0) sred[wm][mi * 16 + g * 4 + i][wn] = p;
        }
    }
    __syncthreads();
    if (tid < 128) {
        int r = tid & 63, w2 = tid >> 6;
        float s = sred[w2][r][0] + sred[w2][r][1] + sred[w2][r][2] + sred[w2][r][3];
        spart[(size_t)nt * kM + m0 + tid] = s;
    }
}

// ---------------------------------------------------------------- softmax over T
__global__ void k_softmax(const float* __restrict__ spart, float* __restrict__ out_align) {
    __shared__ float red[256];
    int b = blockIdx.x, tid = threadIdx.x;
    float v[6];
    float mx = -1e30f;
#pragma unroll
    for (int i = 0; i < 6; ++i) {
        size_t idx = (size_t)b * kT + tid + i * 256;
        float s = spart[idx] + spart[kM + idx] + spart[2 * (size_t)kM + idx] + spart[3 * (size_t)kM + idx];
        v[i] = s; mx = fmaxf(mx, s);
    }
    red[tid] = mx; __syncthreads();
    for (int o = 128; o > 0; o >>= 1) { if (tid < o) red[tid] = fmaxf(red[tid], red[tid + o]); __syncthreads(); }
    mx = red[0]; __syncthreads();
    float sum = 0.f;
#pragma unroll
    for (int i = 0; i < 6; ++i) { v[i] = expf(v[i] - mx); sum += v[i]; }
    red[tid] = sum; __syncthreads();
    for (int o = 128; o > 0; o >>= 1) { if (tid < o) red[tid] += red[tid + o]; __syncthreads(); }
    float inv = 1.f / red[0];
#pragma unroll
    for (int i = 0; i < 6; ++i)
        out_align[(size_t)b * kT + tid + i * 256] = v[i] * inv;
}

// ---------------------------------------------------------------- context (enc f32, L3-hot after k_main)
__global__ void k_ctx_part(const float* __restrict__ enc, const float* __restrict__ align,
                           float* __restrict__ cpart) {
    __shared__ float al[192];
    int ci = blockIdx.x, b = blockIdx.y, tid = threadIdx.x;
    if (tid < 192) al[tid] = align[(size_t)b * kT + ci * 192 + tid];
    __syncthreads();
    float4 acc = {0.f, 0.f, 0.f, 0.f};
    const float* ep = enc + ((size_t)b * kT + (size_t)ci * 192) * kH + tid * 4;
    for (int t = 0; t < 192; ++t) {
        float a = al[t];
        float4 e = *(const float4*)(ep + (size_t)t * kH);
        acc.x += a * e.x; acc.y += a * e.y; acc.z += a * e.z; acc.w += a * e.w;
    }
    *(float4*)&cpart[((size_t)ci * kB + b) * kH + tid * 4] = acc;
}

__global__ void k_ctx_red(const float* __restrict__ cpart, float* __restrict__ out_ctx) {
    int idx = blockIdx.x * 256 + threadIdx.x;
    float s = 0.f;
#pragma unroll
    for (int ci = 0; ci < 8; ++ci) s += cpart[(size_t)ci * kB * kH + idx];
    out_ctx[idx] = s;
}

// ---------------------------------------------------------------- launch
extern "C" void kernel_launch(void* const* d_in, const int* in_sizes, int n_in,
                              void* d_out, int out_size, void* d_ws, size_t ws_size,
                              hipStream_t stream) {
    const float* dec  = (const float*)d_in[0];
    const float* enc  = (const float*)d_in[1];
    const float* la   = (const float*)d_in[2];
    const float* W    = (const float*)d_in[3];
    const float* V    = (const float*)d_in[4];
    const float* U    = (const float*)d_in[5];
    const float* bias = (const float*)d_in[6];
    const float* wv   = (const float*)d_in[7];
    const float* cw   = (const float*)d_in[8];
    const float* cb   = (const float*)d_in[9];

    char* ws = (char*)d_ws;
    f16* Bf      = (f16*)(ws + WS_B);
    f16* locPad  = (f16*)(ws + WS_LOC);
    float* add   = (float*)(ws + WS_ADD);
    float* spart = (float*)(ws + WS_SCORE);
    float* cpart = (float*)(ws + WS_CTXP);

    float* out_ctx   = (float*)d_out;            // (B,H)
    float* out_align = (float*)d_out + kB * kH;  // (B,T)

    hipLaunchKernelGGL(k_prep_b2,  dim3(kC),            dim3(256), 0, stream, V, U, Bf);
    hipLaunchKernelGGL(k_loc,      dim3(kM / 256),      dim3(256), 0, stream, la, cw, cb, locPad);
    hipLaunchKernelGGL(k_prep_add, dim3(kB * 4),        dim3(256), 0, stream, dec, W, bias, add);
    hipLaunchKernelGGL(k_main,     dim3((kM / 128) * 4), dim3(512), 0, stream, enc, Bf, locPad, add, wv, spart);
    hipLaunchKernelGGL(k_softmax,  dim3(kB),            dim3(256), 0, stream, spart, out_align);
    hipLaunchKernelGGL(k_ctx_part, dim3(8, kB),         dim3(256), 0, stream, enc, out_align, cpart);
    hipLaunchKernelGGL(k_ctx_red,  dim3(kB * kH / 256), dim3(256), 0, stream, cpart, out_ctx);
}